// Round 2
// baseline (1175.037 us; speedup 1.0000x reference)
//
#include <hip/hip_runtime.h>

typedef short bx8 __attribute__((ext_vector_type(8)));
typedef float fx4 __attribute__((ext_vector_type(4)));

#define INV 0.08838834764831843f
#define NROWS 200000
#define NT (NROWS / 16)   // 12500 16-row tiles
#define WPB 12            // waves per block
#define NTHREADS (WPB * 64)
#define NBLOCKS 256       // 1 block/CU
#define GW (NBLOCKS * WPB)

__device__ __forceinline__ unsigned short f2bf(float f) {
  unsigned u = __builtin_bit_cast(unsigned, f);
  u += 0x7FFFu + ((u >> 16) & 1u);   // RNE
  return (unsigned short)(u >> 16);
}
__device__ __forceinline__ float sigm(float z) { return 1.0f / (1.0f + __expf(-z)); }
__device__ __forceinline__ unsigned pack2(float a, float b) {
  return (unsigned)f2bf(a) | ((unsigned)f2bf(b) << 16);
}
__device__ __forceinline__ float unpk_lo(unsigned u) {
  return __builtin_bit_cast(float, u << 16);
}
__device__ __forceinline__ float unpk_hi(unsigned u) {
  return __builtin_bit_cast(float, u & 0xFFFF0000u);
}

union FragU { unsigned u[4]; bx8 b; };

// R2: barrier-free per-wave pipeline.
//  - Each wave processes whole 16-row tiles independently (grid-stride by wave).
//  - x loaded straight from global into B-fragment layout (32 dwordx4/lane -> deep MLP).
//  - All weights as pre-built MFMA A/B fragments in LDS (106 KB, staged once, 1 barrier total).
//  - Gating is in-lane (h_v and gates share D-layout); layer-2 act transpose via 8 shfl/block.
//  - Numerics identical to verified baseline: same f2bf RNE, same MFMA chain order, bf16 gates.
__global__ __launch_bounds__(NTHREADS, 3) void nlr_kernel(
    const float* __restrict__ x, const float* __restrict__ w1_s,
    const float* __restrict__ w1_v, const float* __restrict__ w2_s,
    const float* __restrict__ w2_v, float* __restrict__ out) {
  __shared__ short W1S_L[16 * 4 * 64 * 8];  // 64 KB  [jjb][kb][lane][8]
  __shared__ short W1V_L[8 * 4 * 64 * 8];   // 32 KB
  __shared__ short W2S_L[4 * 64 * 8];       //  4 KB  [kb2][lane][8] (B-frag)
  __shared__ short W2V_L[4 * 64 * 8];       //  4 KB

  const int tid = threadIdx.x;
  const int w = tid >> 6;
  const int lane = tid & 63;
  const int quad = lane >> 4;
  const int c16 = lane & 15;

  // ---- stage weight fragments into LDS (once) ----
  for (int p = w; p < 64; p += WPB) {     // w1_s: A-frag, lane holds col j=c16, k=quad*8+jj
    const int jjb = p >> 2, kb = p & 3;
    bx8 f;
#pragma unroll
    for (int jj = 0; jj < 8; ++jj)
      f[jj] = (short)f2bf(w1_s[(kb * 32 + quad * 8 + jj) * 256 + jjb * 16 + c16]);
    *(bx8*)(W1S_L + (p * 64 + lane) * 8) = f;
  }
  for (int p = w; p < 32; p += WPB) {     // w1_v
    const int jjb = p >> 2, kb = p & 3;
    bx8 f;
#pragma unroll
    for (int jj = 0; jj < 8; ++jj)
      f[jj] = (short)f2bf(w1_v[(kb * 32 + quad * 8 + jj) * 128 + jjb * 16 + c16]);
    *(bx8*)(W1V_L + (p * 64 + lane) * 8) = f;
  }
  if (w < 8) {                            // w2_{s,v}: B-frag, lane holds k=quad*8+jj, outcol=c16
    const float* w2 = (w < 4) ? w2_s : w2_v;
    short* dst = (w < 4) ? W2S_L : W2V_L;
    const int kb = w & 3;
    bx8 f;
#pragma unroll
    for (int jj = 0; jj < 8; ++jj)
      f[jj] = (short)f2bf(w2[(kb * 32 + quad * 8 + jj) * 16 + c16]);
    *(bx8*)(dst + (kb * 64 + lane) * 8) = f;
  }
  __syncthreads();  // the only barrier in the kernel

  // act D-layout -> layer-2 A-frag shuffle sources (lanes of same c16, quads 0..3)
  const int srcA = ((quad & 1) << 5) + c16;  // quad 2*(q&1)
  const int srcB = srcA + 16;
  const bool selHi = quad >= 2;

  for (int t = blockIdx.x * WPB + w; t < NT; t += GW) {
    const float* xb = x + (size_t)t * (16 * 512) + c16 * 512;  // this lane's row

    // ---- load raw x: 32 x dwordx4 issued up front (deep MLP) ----
    fx4 rs[8];   // s part: k = kb*32 + quad*8 + h*4 + e
#pragma unroll
    for (int kb = 0; kb < 4; ++kb)
#pragma unroll
      for (int h = 0; h < 2; ++h)
        rs[kb * 2 + h] = *(const fx4*)(xb + kb * 32 + quad * 8 + h * 4);
    fx4 rv[24];  // v part: 24 consecutive floats per (kb): all 3 c for m=quad*8..+7
#pragma unroll
    for (int kb = 0; kb < 4; ++kb)
#pragma unroll
      for (int h = 0; h < 6; ++h)
        rv[kb * 6 + h] = *(const fx4*)(xb + 128 + kb * 96 + quad * 24 + h * 4);

    // ---- convert to B-fragments ----
    bx8 sf[4];
#pragma unroll
    for (int kb = 0; kb < 4; ++kb) {
      bx8 f;
#pragma unroll
      for (int jj = 0; jj < 8; ++jj)
        f[jj] = (short)f2bf(rs[kb * 2 + (jj >> 2)][jj & 3]);
      sf[kb] = f;
    }
    bx8 vf[3][4];
#pragma unroll
    for (int c = 0; c < 3; ++c)
#pragma unroll
      for (int kb = 0; kb < 4; ++kb) {
        bx8 f;
#pragma unroll
        for (int jj = 0; jj < 8; ++jj) {
          const int idx = 3 * jj + c;
          f[jj] = (short)f2bf(rv[kb * 6 + (idx >> 2)][idx & 3]);
        }
        vf[c][kb] = f;
      }

    // ---- layer 1 (s): h_s = W1s^T x; silu -> packed bf16, gates -> packed bf16 ----
    unsigned sA_lo[8], sA_hi[8];  // silu(h_s[:, jb*16..]) D-layout packed pairs
    unsigned gpk[8][2];           // sigmoid gates, bf16 pairs (matches baseline numerics)
#pragma unroll
    for (int jjb = 0; jjb < 16; ++jjb) {
      fx4 a = {0.f, 0.f, 0.f, 0.f};
#pragma unroll
      for (int kb = 0; kb < 4; ++kb) {
        const bx8 Wfr = *(const bx8*)(W1S_L + ((jjb * 4 + kb) * 64 + lane) * 8);
        a = __builtin_amdgcn_mfma_f32_16x16x32_bf16(Wfr, sf[kb], a, 0, 0, 0);
      }
      if (jjb < 8) {
        const float h0 = a[0] * INV, h1 = a[1] * INV, h2 = a[2] * INV, h3 = a[3] * INV;
        sA_lo[jjb] = pack2(h0 * sigm(h0), h1 * sigm(h1));
        sA_hi[jjb] = pack2(h2 * sigm(h2), h3 * sigm(h3));
      } else {
        gpk[jjb - 8][0] = pack2(sigm(a[0] * INV), sigm(a[1] * INV));
        gpk[jjb - 8][1] = pack2(sigm(a[2] * INV), sigm(a[3] * INV));
      }
    }

    // ---- layer 2 (s): out_s = act @ w2_s ----
    fx4 os = {0.f, 0.f, 0.f, 0.f};
#pragma unroll
    for (int kb2 = 0; kb2 < 4; ++kb2) {
      const unsigned a0 = __shfl(sA_lo[2 * kb2], srcA), a1 = __shfl(sA_hi[2 * kb2], srcA);
      const unsigned a2 = __shfl(sA_lo[2 * kb2], srcB), a3 = __shfl(sA_hi[2 * kb2], srcB);
      const unsigned b0 = __shfl(sA_lo[2 * kb2 + 1], srcA), b1 = __shfl(sA_hi[2 * kb2 + 1], srcA);
      const unsigned b2 = __shfl(sA_lo[2 * kb2 + 1], srcB), b3 = __shfl(sA_hi[2 * kb2 + 1], srcB);
      FragU fu;
      fu.u[0] = selHi ? b0 : a0;
      fu.u[1] = selHi ? b1 : a1;
      fu.u[2] = selHi ? b2 : a2;
      fu.u[3] = selHi ? b3 : a3;
      const bx8 Bf = *(const bx8*)(W2S_L + (kb2 * 64 + lane) * 8);
      os = __builtin_amdgcn_mfma_f32_16x16x32_bf16(fu.b, Bf, os, 0, 0, 0);
    }

    // ---- v paths: h_v, in-lane gating, layer 2 (v) ----
    fx4 ov[3];
#pragma unroll
    for (int c = 0; c < 3; ++c) {
      unsigned vA_lo[8], vA_hi[8];
#pragma unroll
      for (int jjb = 0; jjb < 8; ++jjb) {
        fx4 a = {0.f, 0.f, 0.f, 0.f};
#pragma unroll
        for (int kb = 0; kb < 4; ++kb) {
          const bx8 Wfr = *(const bx8*)(W1V_L + ((jjb * 4 + kb) * 64 + lane) * 8);
          a = __builtin_amdgcn_mfma_f32_16x16x32_bf16(Wfr, vf[c][kb], a, 0, 0, 0);
        }
        const float g0 = unpk_lo(gpk[jjb][0]), g1 = unpk_hi(gpk[jjb][0]);
        const float g2 = unpk_lo(gpk[jjb][1]), g3 = unpk_hi(gpk[jjb][1]);
        vA_lo[jjb] = pack2(a[0] * INV * g0, a[1] * INV * g1);
        vA_hi[jjb] = pack2(a[2] * INV * g2, a[3] * INV * g3);
      }
      fx4 o = {0.f, 0.f, 0.f, 0.f};
#pragma unroll
      for (int kb2 = 0; kb2 < 4; ++kb2) {
        const unsigned a0 = __shfl(vA_lo[2 * kb2], srcA), a1 = __shfl(vA_hi[2 * kb2], srcA);
        const unsigned a2 = __shfl(vA_lo[2 * kb2], srcB), a3 = __shfl(vA_hi[2 * kb2], srcB);
        const unsigned b0 = __shfl(vA_lo[2 * kb2 + 1], srcA), b1 = __shfl(vA_hi[2 * kb2 + 1], srcA);
        const unsigned b2 = __shfl(vA_lo[2 * kb2 + 1], srcB), b3 = __shfl(vA_hi[2 * kb2 + 1], srcB);
        FragU fu;
        fu.u[0] = selHi ? b0 : a0;
        fu.u[1] = selHi ? b1 : a1;
        fu.u[2] = selHi ? b2 : a2;
        fu.u[3] = selHi ? b3 : a3;
        const bx8 Bf = *(const bx8*)(W2V_L + (kb2 * 64 + lane) * 8);
        o = __builtin_amdgcn_mfma_f32_16x16x32_bf16(fu.b, Bf, o, 0, 0, 0);
      }
      ov[c] = o;
    }

    // ---- stores: D2 layout col=c16=outcol, row=quad*4+r=n ----
    const size_t nb = (size_t)t * 16 + quad * 4;
#pragma unroll
    for (int r = 0; r < 4; ++r) {
      float* orow = out + (nb + r) * 64;
      orow[c16] = os[r] * INV;
      orow[16 + 3 * c16 + 0] = ov[0][r] * INV;
      orow[16 + 3 * c16 + 1] = ov[1][r] * INV;
      orow[16 + 3 * c16 + 2] = ov[2][r] * INV;
    }
  }
}

extern "C" void kernel_launch(void* const* d_in, const int* in_sizes, int n_in,
                              void* d_out, int out_size, void* d_ws, size_t ws_size,
                              hipStream_t stream) {
  const float* x    = (const float*)d_in[0];
  const float* w1_s = (const float*)d_in[1];
  const float* w1_v = (const float*)d_in[2];
  const float* w2_s = (const float*)d_in[3];
  const float* w2_v = (const float*)d_in[4];
  nlr_kernel<<<NBLOCKS, NTHREADS, 0, stream>>>(x, w1_s, w1_v, w2_s, w2_v, (float*)d_out);
}

// Round 3
// 607.575 us; speedup vs baseline: 1.9340x; 1.9340x over previous
//
#include <hip/hip_runtime.h>

typedef short bx8 __attribute__((ext_vector_type(8)));
typedef unsigned short ux4 __attribute__((ext_vector_type(4)));
typedef float fx4 __attribute__((ext_vector_type(4)));

#define INV 0.08838834764831843f
#define TR 16
#define NROWS 200000
#define NT (NROWS / TR)      // 12500 tiles
#define NTHREADS 640         // 10 waves
#define NBLOCKS 256          // 1 block/CU, grid-stride
#define LP32 540             // f32 LDS row stride (2048B data + 112B pad; 540%32=28 -> ~2-way banks)
#define XBUF (TR * LP32)     // 8640 floats per tile buffer
#define LPA 136              // bf16 row stride for ACT/GS
#define LPO 68               // f32 row stride for OUT staging (68%32=4 -> 2-way banks)

// async global->LDS, 16B per lane, dest = uniform base + lane*16 (m97 pattern)
#define GL16(gp, lp)                                                   \
  __builtin_amdgcn_global_load_lds(                                    \
      (const __attribute__((address_space(1))) unsigned*)(gp),         \
      (__attribute__((address_space(3))) unsigned*)(lp), 16, 0, 0)
#define FENCE() asm volatile("" ::: "memory")
#define WAITL0() asm volatile("s_waitcnt lgkmcnt(0)" ::: "memory")
// barrier WITHOUT vmcnt drain: prefetch loads stay in flight (T4 counted-vmcnt)
#define BARRIER()                  \
  do {                             \
    WAITL0();                      \
    __builtin_amdgcn_s_barrier();  \
    FENCE();                       \
  } while (0)

__device__ __forceinline__ unsigned short f2bf(float f) {
  unsigned u = __builtin_bit_cast(unsigned, f);
  u += 0x7FFFu + ((u >> 16) & 1u);  // RNE
  return (unsigned short)(u >> 16);
}
__device__ __forceinline__ float bf2f(unsigned short h) {
  unsigned u = ((unsigned)h) << 16;
  return __builtin_bit_cast(float, u);
}
__device__ __forceinline__ float sigm(float z) { return 1.0f / (1.0f + __expf(-z)); }

// R3: R0's verified cooperative phase structure + async f32 staging.
//  - x staged raw (f32) via global_load_lds, triple-buffered, 2 tiles prefetch depth.
//  - Counted vmcnt(8) waits; raw s_barrier (no vmcnt drain) -> loads always in flight.
//  - f32->bf16 conversion during fragment assembly (numerics identical to R0).
//  - Output staged in LDS, flushed as full 256B rows by waves 8,9 (kills 16x write amp).
// Roles: staging issue w0-7 (2 rows each); L1 all waves (s: w0-3, v: w4-9);
//        gates w2-3; act w0-1; gated_v w4-9; L2+OUT w0-3; OUT flush w8-9.
__global__ __launch_bounds__(NTHREADS) void nlr_kernel(
    const float* __restrict__ x, const float* __restrict__ w1_s,
    const float* __restrict__ w1_v, const float* __restrict__ w2_s,
    const float* __restrict__ w2_v, float* __restrict__ out) {
  __shared__ __align__(16) float XF[3 * XBUF];        // 103680 B
  __shared__ __align__(16) short ACTL[4 * TR * LPA];  //  17408 B
  __shared__ __align__(16) short GSL[TR * LPA];       //   4352 B
  __shared__ __align__(16) float OUTB[TR * LPO];      //   4352 B  (total 129792 B)

  const int tid = threadIdx.x;
  const int w = tid >> 6;
  const int lane = tid & 63;
  const int quad = lane >> 4;
  const int c16 = lane & 15;
  const int mrow0 = quad * 8;

  // wave w (<8) stages rows 2w, 2w+1 of a tile: 4 x 1KB coalesced instructions
  auto issue = [&](int t, int buf) {
    const float* gb = x + (size_t)t * (TR * 512) + 2 * w * 512 + lane * 4;
    float* lb = XF + buf * XBUF + 2 * w * LP32;
#pragma unroll
    for (int j = 0; j < 4; ++j) {
      const int row = j >> 1, half = j & 1;
      GL16(gb + row * 512 + half * 256, lb + row * LP32 + half * 256);
    }
  };

  // ---- prologue prefetch: tiles 0,1 for this block (issued before weight build) ----
  if (w < 8) {
    if ((int)blockIdx.x < NT) issue(blockIdx.x, 0);
    if ((int)blockIdx.x + NBLOCKS < NT) issue(blockIdx.x + NBLOCKS, 1);
  }

  // ---- build layer-1 weight A-fragments in VGPRs (once) ----
  bx8 Wf[4][4];  // [jjb][kb]
  if (w < 4) {   // s-waves: h_s cols [w*64, w*64+64)
#pragma unroll
    for (int jjb = 0; jjb < 4; ++jjb) {
      const int col = (w * 4 + jjb) * 16 + c16;
#pragma unroll
      for (int kb = 0; kb < 4; ++kb) {
        bx8 f;
#pragma unroll
        for (int jj = 0; jj < 8; ++jj)
          f[jj] = (short)f2bf(w1_s[(kb * 32 + mrow0 + jj) * 256 + col]);
        Wf[jjb][kb] = f;
      }
    }
  } else {       // v-waves: c = (w-4)>>1, half = (w-4)&1
    const int half = (w - 4) & 1;
#pragma unroll
    for (int jjb = 0; jjb < 4; ++jjb) {
      const int col = (half * 4 + jjb) * 16 + c16;
#pragma unroll
      for (int kb = 0; kb < 4; ++kb) {
        bx8 f;
#pragma unroll
        for (int jj = 0; jj < 8; ++jj)
          f[jj] = (short)f2bf(w1_v[(kb * 32 + mrow0 + jj) * 128 + col]);
        Wf[jjb][kb] = f;
      }
    }
  }
  bx8 W2f[4];  // layer-2 A-fragments (w0: w2_s; w1-3: w2_v)
  if (w < 4) {
    const float* w2 = (w == 0) ? w2_s : w2_v;
#pragma unroll
    for (int kb = 0; kb < 4; ++kb) {
      bx8 f;
#pragma unroll
      for (int jj = 0; jj < 8; ++jj)
        f[jj] = (short)f2bf(w2[(kb * 32 + mrow0 + jj) * 16 + c16]);
      W2f[kb] = f;
    }
  }

  int tile = blockIdx.x;
  int p = 0;
  while (tile < NT) {
    // ---- issue tile t+2 (depth-2 prefetch), counted wait for tile t ----
    const bool h2 = tile + 2 * NBLOCKS < NT;
    const bool h1 = tile + NBLOCKS < NT;
    if (h2 && w < 8) {
      int p2 = p + 2; if (p2 >= 3) p2 -= 3;
      issue(tile + 2 * NBLOCKS, p2);
    }
    if (w < 8) {  // staging waves carry pure-load vmcnt streams -> exact counts
      if (h2)      asm volatile("s_waitcnt vmcnt(8)" ::: "memory");
      else if (h1) asm volatile("s_waitcnt vmcnt(4)" ::: "memory");
      else         asm volatile("s_waitcnt vmcnt(0)" ::: "memory");
    }
    __builtin_amdgcn_sched_barrier(0);
    BARRIER();  // B1: XF[p] ready; prior-iter ACT/GS/OUT writes visible

    // ---- flush previous tile's OUT (waves 8,9; full 256B rows, coalesced) ----
    if (w >= 8 && tile != (int)blockIdx.x) {
      const int tprev = tile - NBLOCKS;
      float* og = out + (size_t)tprev * (TR * 64);
      const int rbase = (w - 8) * 8;
#pragma unroll
      for (int j = 0; j < 2; ++j) {
        const int row = rbase + j * 4 + quad;
        const fx4 v = *(const fx4*)(OUTB + row * LPO + c16 * 4);
        *(fx4*)(og + row * 64 + c16 * 4) = v;
      }
    }

    // ---- phase B: layer 1 (all 10 waves); fragments assembled from f32 LDS ----
    fx4 acc[4];
    {
      bx8 B[4];
      if (w < 4) {  // s: k contiguous -> 2x b128 per kb
        const float* xr = XF + p * XBUF + c16 * LP32;
#pragma unroll
        for (int kb = 0; kb < 4; ++kb) {
          const fx4 u0 = *(const fx4*)(xr + kb * 32 + mrow0);
          const fx4 u1 = *(const fx4*)(xr + kb * 32 + mrow0 + 4);
          bx8 f;
          f[0] = (short)f2bf(u0[0]); f[1] = (short)f2bf(u0[1]);
          f[2] = (short)f2bf(u0[2]); f[3] = (short)f2bf(u0[3]);
          f[4] = (short)f2bf(u1[0]); f[5] = (short)f2bf(u1[1]);
          f[6] = (short)f2bf(u1[2]); f[7] = (short)f2bf(u1[3]);
          B[kb] = f;
        }
      } else {      // v: stride-3 de-interleave during read (8x b32 per kb, ~2-way banks)
        const int c = (w - 4) >> 1;
        const float* xr = XF + p * XBUF + c16 * LP32 + 128 + c;
#pragma unroll
        for (int kb = 0; kb < 4; ++kb) {
          const float* q = xr + 3 * (kb * 32 + mrow0);
          bx8 f;
#pragma unroll
          for (int jj = 0; jj < 8; ++jj) f[jj] = (short)f2bf(q[3 * jj]);
          B[kb] = f;
        }
      }
#pragma unroll
      for (int jjb = 0; jjb < 4; ++jjb) {
        fx4 a = {0.f, 0.f, 0.f, 0.f};
#pragma unroll
        for (int kb = 0; kb < 4; ++kb)
          a = __builtin_amdgcn_mfma_f32_16x16x32_bf16(Wf[jjb][kb], B[kb], a, 0, 0, 0);
        acc[jjb] = a;
      }
    }
    if (w == 2 || w == 3) {  // gate cols 128..255 -> sigmoid -> GS (bf16, as baseline)
#pragma unroll
      for (int jjb = 0; jjb < 4; ++jjb) {
        const int jb = w * 4 + jjb;  // 8..15
        ux4 pk;
#pragma unroll
        for (int r = 0; r < 4; ++r) pk[r] = f2bf(sigm(acc[jjb][r] * INV));
        *(ux4*)(GSL + c16 * LPA + (jb - 8) * 16 + quad * 4) = pk;
      }
    }
    BARRIER();  // B2: gates visible; XF[p] reads done

    // ---- phase C: act (w0,1) / gated_v (w4-9) -> ACT ----
    if (w < 2) {
#pragma unroll
      for (int jjb = 0; jjb < 4; ++jjb) {
        const int jb = w * 4 + jjb;  // 0..7
        ux4 pk;
#pragma unroll
        for (int r = 0; r < 4; ++r) {
          const float h = acc[jjb][r] * INV;
          pk[r] = f2bf(h * sigm(h));
        }
        *(ux4*)(ACTL + c16 * LPA + jb * 16 + quad * 4) = pk;
      }
    } else if (w >= 4) {
      const int vc = (w - 4) >> 1, half = (w - 4) & 1;
      short* gv = ACTL + (1 + vc) * TR * LPA;
#pragma unroll
      for (int jjb = 0; jjb < 4; ++jjb) {
        const int jb = half * 4 + jjb;  // 0..7 (k-block)
        const ux4 g = *(const ux4*)(GSL + c16 * LPA + jb * 16 + quad * 4);
        ux4 pk;
#pragma unroll
        for (int r = 0; r < 4; ++r)
          pk[r] = f2bf(acc[jjb][r] * INV * bf2f(g[r]));
        *(ux4*)(gv + c16 * LPA + jb * 16 + quad * 4) = pk;
      }
    }
    BARRIER();  // B3: ACT visible

    // ---- phase D: layer 2 (w0-3), results to OUT LDS staging ----
    if (w < 4) {
      const short* src = ACTL + w * TR * LPA;
      fx4 a = {0.f, 0.f, 0.f, 0.f};
      const int rb = c16 * LPA + mrow0;
#pragma unroll
      for (int kb = 0; kb < 4; ++kb) {
        const bx8 Bf = *(const bx8*)(src + rb + kb * 32);
        a = __builtin_amdgcn_mfma_f32_16x16x32_bf16(W2f[kb], Bf, a, 0, 0, 0);
      }
      if (w == 0) {  // out_s: row c16, cols quad*4..+3
        fx4 o = {a[0] * INV, a[1] * INV, a[2] * INV, a[3] * INV};
        *(fx4*)(OUTB + c16 * LPO + quad * 4) = o;
      } else {       // out_v component c=w-1: col 16 + 3*(quad*4+r) + c
        const int c = w - 1;
#pragma unroll
        for (int r = 0; r < 4; ++r)
          OUTB[c16 * LPO + 16 + 3 * (quad * 4 + r) + c] = a[r] * INV;
      }
    }
    // no barrier: OUT rewrite vs flush is separated by B1+B2 of next iteration;
    // XF[p_next] issue target was last read before B2 two iterations ago.
    tile += NBLOCKS;
    p = (p + 1 == 3) ? 0 : p + 1;
  }

  // ---- epilogue: flush the final tile's OUT ----
  BARRIER();
  if (w >= 8) {
    const int tlast = tile - NBLOCKS;
    float* og = out + (size_t)tlast * (TR * 64);
    const int rbase = (w - 8) * 8;
#pragma unroll
    for (int j = 0; j < 2; ++j) {
      const int row = rbase + j * 4 + quad;
      const fx4 v = *(const fx4*)(OUTB + row * LPO + c16 * 4);
      *(fx4*)(og + row * 64 + c16 * 4) = v;
    }
  }
}

extern "C" void kernel_launch(void* const* d_in, const int* in_sizes, int n_in,
                              void* d_out, int out_size, void* d_ws, size_t ws_size,
                              hipStream_t stream) {
  const float* x    = (const float*)d_in[0];
  const float* w1_s = (const float*)d_in[1];
  const float* w1_v = (const float*)d_in[2];
  const float* w2_s = (const float*)d_in[3];
  const float* w2_v = (const float*)d_in[4];
  nlr_kernel<<<NBLOCKS, NTHREADS, 0, stream>>>(x, w1_s, w1_v, w2_s, w2_v, (float*)d_out);
}